// Round 3
// baseline (1518.888 us; speedup 1.0000x reference)
//
#include <hip/hip_runtime.h>

// Problem: VOCAB=32000, H=1024, L=256, B=64.  Only batch row 0 matters
// (reference broadcasts hs[:, :1, :]), so this is a single-sequence GRU.

typedef float f32x4 __attribute__((ext_vector_type(4)));

__device__ __forceinline__ float sigf(float x) { return 1.0f / (1.0f + __expf(-x)); }
__device__ __forceinline__ float tanh_fast(float x) {
  float e = __expf(2.0f * x);
  return 1.0f - 2.0f / (e + 1.0f);
}

// ---------- K1 (v1): gi[t][j] = emb[x[t][0]] . w_ih[j] + b_ih[j] (+ b_hh[j] for j<2048) ----------
// grid 768 blocks (4 j-rows each) x 256 thr (thread = t). 3 blocks/CU for latency hiding.
// R1 post-mortem: LDS-staged variant with 1 block/CU was +78 us WORSE — the scattered
// emb reads are L2-resident (256 rows = 1 MB) and 12 waves/CU hide the latency.
__global__ __launch_bounds__(256) void k1_gi(const int* __restrict__ x,
                                             const float* __restrict__ emb,
                                             const float* __restrict__ w_ih,
                                             const float* __restrict__ b_ih,
                                             const float* __restrict__ b_hh,
                                             float* __restrict__ gi)
{
  const int j0 = blockIdx.x * 4;
  const int t  = threadIdx.x;
  const int idx = x[t * 64];                       // x[t][0]
  const float* er = emb + (size_t)idx * 1024;

  float acc[4];
#pragma unroll
  for (int j = 0; j < 4; ++j) {
    const int jj = j0 + j;
    acc[j] = b_ih[jj] + (jj < 2048 ? b_hh[jj] : 0.0f);  // fold b_hh for r,z gates
  }

  for (int kc = 0; kc < 1024; kc += 16) {
    const float4 e0 = *(const float4*)(er + kc);
    const float4 e1 = *(const float4*)(er + kc + 4);
    const float4 e2 = *(const float4*)(er + kc + 8);
    const float4 e3 = *(const float4*)(er + kc + 12);
    const float e[16] = {e0.x, e0.y, e0.z, e0.w, e1.x, e1.y, e1.z, e1.w,
                         e2.x, e2.y, e2.z, e2.w, e3.x, e3.y, e3.z, e3.w};
#pragma unroll
    for (int j = 0; j < 4; ++j) {
      const float* w = w_ih + (size_t)(j0 + j) * 1024 + kc;  // wave-uniform -> s_load
#pragma unroll
      for (int i = 0; i < 16; ++i) acc[j] = fmaf(e[i], w[i], acc[j]);
    }
  }
  *(float4*)(gi + (size_t)t * 3072 + j0) = make_float4(acc[0], acc[1], acc[2], acc[3]);
}

// ---------- K2 v3: persistent recurrence with flag-based sync ----------
// grid 128 x 512 (8 waves). Wave wv of block g owns h element hj = 8g+wv; its three
// w_hh rows live in 48 fp32 VGPRs per lane.
// R2 post-mortem: sentinel polling burned ~9-10 poll rounds/step — 8192 L2-bypass
// line-requests/round to the same 64 lines (128 req/line) convoy at L3.
// v3 sync: producers store h values (sc0 sc1, vmcnt-drained) -> barrier -> tid0
// stores flags[g]=t+1 (release pattern: values globally visible before flag).
// Consumers: ONLY wave 0 polls, and only the 512B flag array (1024 line-req/round,
// 8x less traffic; waves 1-7 idle silently at the barrier). On flags>=t, row t-1 is
// complete -> ONE bulk 4KB read (no data re-poll), distribute via LDS.
// Rows are write-once per step, flags monotonic 0..256 -> no ABA, no sentinels,
// no 1MB memset.
__global__ __launch_bounds__(512) void k2_rec(const float* __restrict__ w_hh,
                                              const float* __restrict__ b_hh,
                                              const float* __restrict__ gi,
                                              const float* __restrict__ w_out,
                                              float* __restrict__ hseq,
                                              unsigned int* __restrict__ flags,
                                              float* __restrict__ acc)
{
  __shared__ float hlds[1024];   // 4 KB

  const int g    = blockIdx.x;
  const int tid  = threadIdx.x;
  const int wv   = tid >> 6;
  const int lane = tid & 63;
  const int hj   = __builtin_amdgcn_readfirstlane(g * 8 + wv);  // uniform -> s_loads

  // ---- weights into VGPRs: w[gate*4+j] holds row[j*256 + lane*4 .. +3] ----
  float4 w[12];
#pragma unroll
  for (int gate = 0; gate < 3; ++gate) {
    const float* row = w_hh + (size_t)(gate * 1024 + hj) * 1024;
#pragma unroll
    for (int j = 0; j < 4; ++j)
      w[gate * 4 + j] = *(const float4*)(row + j * 256 + lane * 4);
  }
  const float bhh_n = b_hh[2048 + hj];
  float hp = 0.0f, wout_acc = 0.0f;

  const unsigned long long* fl64 = (const unsigned long long*)flags;

#pragma unroll 1
  for (int t = 0; t < 256; ++t) {
    // wave-uniform scalar prefetches (overlap the poll round-trip)
    const float gi_r = gi[(size_t)t * 3072 + hj];
    const float gi_z = gi[(size_t)t * 3072 + 1024 + hj];
    const float gi_n = gi[(size_t)t * 3072 + 2048 + hj];
    const float wo   = w_out[(size_t)t * 1024 + hj];

    float ar = 0.f, az = 0.f, an = 0.f;

    if (t > 0) {
      if (wv == 0) {
        // poll the 128 block-flags (2 per lane): flag[g'] >= t  <=>  g' finished t-1
        const unsigned long long* fp = fl64 + lane;
        const unsigned int tt = (unsigned int)t;
        for (;;) {
          unsigned long long v;
          asm volatile("global_load_dwordx2 %0, %1, off sc0 sc1\n\t"
                       "s_waitcnt vmcnt(0)"
                       : "=v"(v) : "v"(fp) : "memory");
          const bool ok = (((unsigned int)v) >= tt) & (((unsigned int)(v >> 32)) >= tt);
          if (__all(ok)) break;
        }
        // flags passed -> row t-1 fully visible: ONE bulk read of 4KB
        const float* p0 = hseq + (size_t)(t - 1) * 1024 + lane * 4;
        f32x4 r0, r1, r2, r3;
        asm volatile("global_load_dwordx4 %0, %4, off sc0 sc1\n\t"
                     "global_load_dwordx4 %1, %4, off offset:1024 sc0 sc1\n\t"
                     "global_load_dwordx4 %2, %4, off offset:2048 sc0 sc1\n\t"
                     "global_load_dwordx4 %3, %4, off offset:3072 sc0 sc1\n\t"
                     "s_waitcnt vmcnt(0)"
                     : "=v"(r0), "=v"(r1), "=v"(r2), "=v"(r3)
                     : "v"(p0) : "memory");
        f32x4* hv = (f32x4*)hlds;            // hlds[q*256 + lane*4] = rq
        hv[lane]       = r0;
        hv[64 + lane]  = r1;
        hv[128 + lane] = r2;
        hv[192 + lane] = r3;
      }
      __syncthreads();                        // barrier1: hlds fully valid

      // dot: lane owns k = j*256 + lane*4 + c
#pragma unroll
      for (int j = 0; j < 4; ++j) {
        const float4 h4 = *(const float4*)&hlds[j * 256 + lane * 4];
        const float4 wr = w[j], wz = w[4 + j], wn = w[8 + j];
        ar = fmaf(h4.x, wr.x, ar); ar = fmaf(h4.y, wr.y, ar);
        ar = fmaf(h4.z, wr.z, ar); ar = fmaf(h4.w, wr.w, ar);
        az = fmaf(h4.x, wz.x, az); az = fmaf(h4.y, wz.y, az);
        az = fmaf(h4.z, wz.z, az); az = fmaf(h4.w, wz.w, az);
        an = fmaf(h4.x, wn.x, an); an = fmaf(h4.y, wn.y, an);
        an = fmaf(h4.z, wn.z, an); an = fmaf(h4.w, wn.w, an);
      }
#pragma unroll
      for (int m = 1; m < 64; m <<= 1) {
        ar += __shfl_xor(ar, m, 64);
        az += __shfl_xor(az, m, 64);
        an += __shfl_xor(an, m, 64);
      }
    }

    const float r  = sigf(ar + gi_r);               // b_ih+b_hh folded into gi_r/gi_z
    const float z  = sigf(az + gi_z);
    const float n  = tanh_fast(gi_n + r * (an + bhh_n));
    const float h2 = (1.0f - z) * n + z * hp;

    if (lane == 0) {
      // value store, drained to the coherence point before this wave hits barrier2
      float* vp = hseq + (size_t)t * 1024 + hj;
      asm volatile("global_store_dword %0, %1, off sc0 sc1\n\t"
                   "s_waitcnt vmcnt(0)"
                   :: "v"(vp), "v"(h2) : "memory");
      wout_acc = fmaf(h2, wo, wout_acc);            // fold w_out dot in
    }
    hp = h2;

    __syncthreads();                                // barrier2: all 8 values visible
    if (tid == 0) {                                 // release: flag after values
      unsigned int fv = (unsigned int)(t + 1);
      unsigned int* fp = flags + g;
      asm volatile("global_store_dword %0, %1, off sc0 sc1"
                   :: "v"(fp), "v"(fv) : "memory");
    }
    // WAR on hlds is safe: wave0 refills only after barrier2 of this step.
  }

  if (lane == 0) atomicAdd(acc, wout_acc);
}

// ---------- K3: pure feat broadcast: feat[b][i] = hseq[i] for all 64 b ----------
__global__ __launch_bounds__(256) void k3_bcast(const float* __restrict__ hseq_f,
                                                float* __restrict__ outbuf)
{
  const int gtid = blockIdx.x * 256 + threadIdx.x;
  const float4* src = (const float4*)hseq_f;    // 65536 float4
  float4* dst = (float4*)outbuf;
  for (int q = gtid; q < 64 * 65536; q += 1024 * 256) {
    const int b = q >> 16, i4 = q & 65535;
    dst[(size_t)b * 65536 + i4] = src[i4];
  }
}

// ---------- K4: out[b] = sigmoid(acc + b_out) for all 64 b ----------
__global__ void k4_fin(const float* __restrict__ acc, const float* __restrict__ b_out,
                       float* __restrict__ outbuf)
{
  const float s = sigf(acc[0] + b_out[0]);
  outbuf[(size_t)16777216 + threadIdx.x] = s;
}

// ---------- launch ----------
extern "C" void kernel_launch(void* const* d_in, const int* in_sizes, int n_in,
                              void* d_out, int out_size, void* d_ws, size_t ws_size,
                              hipStream_t stream) {
  const int*   x     = (const int*)d_in[0];
  const float* emb   = (const float*)d_in[1];
  const float* w_ih  = (const float*)d_in[2];
  const float* w_hh  = (const float*)d_in[3];
  const float* b_ih  = (const float*)d_in[4];
  const float* b_hh  = (const float*)d_in[5];
  const float* w_out = (const float*)d_in[6];
  const float* b_out = (const float*)d_in[7];
  float* out = (float*)d_out;

  char* ws = (char*)d_ws;
  float*        gi    = (float*)ws;                       // 3,145,728 B
  float*        hseq  = (float*)(ws + 3145728);           // 1,048,576 B
  unsigned int* flags = (unsigned int*)(ws + 4194304);    // 512 B (128 u32)
  float*        acc   = (float*)(ws + 4194816);           // 4 B

  hipMemsetAsync(ws + 4194304, 0, 516, stream);           // flags + acc in one shot

  hipLaunchKernelGGL(k1_gi,    dim3(768),  dim3(256), 0, stream, x, emb, w_ih, b_ih, b_hh, gi);
  hipLaunchKernelGGL(k2_rec,   dim3(128),  dim3(512), 0, stream, w_hh, b_hh, gi, w_out, hseq, flags, acc);
  hipLaunchKernelGGL(k3_bcast, dim3(1024), dim3(256), 0, stream, hseq, out);
  hipLaunchKernelGGL(k4_fin,   dim3(1),    dim3(64),  0, stream, acc, b_out, out);
}

// Round 4
// 1202.757 us; speedup vs baseline: 1.2628x; 1.2628x over previous
//
#include <hip/hip_runtime.h>

// Problem: VOCAB=32000, H=1024, L=256, B=64.  Only batch row 0 matters
// (reference broadcasts hs[:, :1, :]), so this is a single-sequence GRU.
#define SENT 0xAAAAAAAAu

typedef float f32x4 __attribute__((ext_vector_type(4)));

__device__ __forceinline__ float sigf(float x) { return 1.0f / (1.0f + __expf(-x)); }
__device__ __forceinline__ float tanh_fast(float x) {
  float e = __expf(2.0f * x);
  return 1.0f - 2.0f / (e + 1.0f);
}

// ---------- K1 (v1): gi[t][j] = emb[x[t][0]] . w_ih[j] + b_ih[j] (+ b_hh[j] for j<2048) ----------
// grid 768 blocks (4 j-rows each) x 256 thr (thread = t). 3 blocks/CU for latency hiding.
// R1: LDS-staged variant was +78 us WORSE (emb rows are L2-resident; 12 waves/CU hide it).
__global__ __launch_bounds__(256) void k1_gi(const int* __restrict__ x,
                                             const float* __restrict__ emb,
                                             const float* __restrict__ w_ih,
                                             const float* __restrict__ b_ih,
                                             const float* __restrict__ b_hh,
                                             float* __restrict__ gi)
{
  const int j0 = blockIdx.x * 4;
  const int t  = threadIdx.x;
  const int idx = x[t * 64];                       // x[t][0]
  const float* er = emb + (size_t)idx * 1024;

  float acc[4];
#pragma unroll
  for (int j = 0; j < 4; ++j) {
    const int jj = j0 + j;
    acc[j] = b_ih[jj] + (jj < 2048 ? b_hh[jj] : 0.0f);  // fold b_hh for r,z gates
  }

  for (int kc = 0; kc < 1024; kc += 16) {
    const float4 e0 = *(const float4*)(er + kc);
    const float4 e1 = *(const float4*)(er + kc + 4);
    const float4 e2 = *(const float4*)(er + kc + 8);
    const float4 e3 = *(const float4*)(er + kc + 12);
    const float e[16] = {e0.x, e0.y, e0.z, e0.w, e1.x, e1.y, e1.z, e1.w,
                         e2.x, e2.y, e2.z, e2.w, e3.x, e3.y, e3.z, e3.w};
#pragma unroll
    for (int j = 0; j < 4; ++j) {
      const float* w = w_ih + (size_t)(j0 + j) * 1024 + kc;  // wave-uniform -> s_load
#pragma unroll
      for (int i = 0; i < 16; ++i) acc[j] = fmaf(e[i], w[i], acc[j]);
    }
  }
  *(float4*)(gi + (size_t)t * 3072 + j0) = make_float4(acc[0], acc[1], acc[2], acc[3]);
}

// ---------- K2 v4: persistent recurrence, sentinel sync, 32-block sync domain ----------
// R3 post-mortem: flag-based release sync (3 serialized L3 RTs/step) was 1.7x WORSE
// than sentinel-in-data (whose poll load IS the data read, and whose producer store
// is fire-and-forget). Sentinel scheme restored.
// R4 change: shrink the sync domain 4x. 32 blocks x 512 thr (8 waves). Wave wv of
// block g owns FOUR contiguous h elements hj0=(g*8+wv)*4 .. +3; its 12 w_hh rows
// (3 gates x 4 rows) live in 192 fp32 regs per lane (AGPR-banked by the compiler).
// Poll structure per block is unchanged (8 waves x 128-word chunks of h[t-1], u64
// sentinel polls, LDS share) but device-wide there are now 256 polling waves
// instead of 1024 (2048 line-req/round vs 8192) and 256 vectorized dwordx4 producer
// stores instead of 1024 scalar ones. Step time = max over producers + detection
// quantization, both of which scale with participant count.
__global__ __launch_bounds__(512) void k2_rec(const float* __restrict__ w_hh,
                                              const float* __restrict__ b_hh,
                                              const float* __restrict__ gi,
                                              const float* __restrict__ w_out,
                                              unsigned int* __restrict__ hseq,
                                              float* __restrict__ acc)
{
  __shared__ float hlds[1024];   // 4 KB

  const int g    = blockIdx.x;                    // 0..31
  const int tid  = threadIdx.x;
  const int wv   = tid >> 6;                      // 0..7
  const int lane = tid & 63;
  const int hj0  = __builtin_amdgcn_readfirstlane((g * 8 + wv) * 4);  // uniform

  // ---- weights: w[gate][q][j] = w_hh[(gate*1024 + hj0+q)*1024 + j*256 + lane*4 ..+3]
  f32x4 w[3][4][4];                               // 192 floats/lane
#pragma unroll
  for (int gate = 0; gate < 3; ++gate)
#pragma unroll
    for (int q = 0; q < 4; ++q) {
      const float* row = w_hh + (size_t)(gate * 1024 + hj0 + q) * 1024;
#pragma unroll
      for (int j = 0; j < 4; ++j)
        w[gate][q][j] = *(const f32x4*)(row + j * 256 + lane * 4);
    }

  float bn[4], hp[4];
#pragma unroll
  for (int q = 0; q < 4; ++q) { bn[q] = b_hh[2048 + hj0 + q]; hp[q] = 0.0f; }
  float wout_acc = 0.0f;

  const unsigned long long* hs64 = (const unsigned long long*)hseq;

#pragma unroll 1
  for (int t = 0; t < 256; ++t) {
    // wave-uniform scalar prefetches (overlap the poll round-trip)
    float gi_r[4], gi_z[4], gi_n[4], wo[4];
#pragma unroll
    for (int q = 0; q < 4; ++q) {
      gi_r[q] = gi[(size_t)t * 3072 + hj0 + q];
      gi_z[q] = gi[(size_t)t * 3072 + 1024 + hj0 + q];
      gi_n[q] = gi[(size_t)t * 3072 + 2048 + hj0 + q];
      wo[q]   = w_out[(size_t)t * 1024 + hj0 + q];
    }

    float a[3][4];
#pragma unroll
    for (int gate = 0; gate < 3; ++gate)
#pragma unroll
      for (int q = 0; q < 4; ++q) a[gate][q] = 0.0f;

    if (t > 0) {
      // poll own 512 B chunk of row t-1: one coalesced plain dwordx2 (sc0 sc1) per
      // lane per round; values are {SENT | final} so no atomicity needed, and a
      // successful poll IS the data read (detection overlapped with arrival).
      const unsigned long long* p = hs64 + (size_t)(t - 1) * 512 + wv * 64 + lane;
      unsigned long long v;
      for (;;) {
        asm volatile("global_load_dwordx2 %0, %1, off sc0 sc1\n\t"
                     "s_waitcnt vmcnt(0)"
                     : "=v"(v) : "v"(p) : "memory");
        const bool ok = (((unsigned int)v) != SENT) &
                        (((unsigned int)(v >> 32)) != SENT);
        if (__all(ok)) break;
      }
      const int w0 = wv * 128 + lane * 2;          // 8B-aligned -> ds_write_b64
      hlds[w0]     = __uint_as_float((unsigned int)v);
      hlds[w0 + 1] = __uint_as_float((unsigned int)(v >> 32));
      __syncthreads();                              // barrier1: hlds fully valid

      // dots: lane owns k = j*256 + lane*4 + c; 192 FMA, h4 reused across 12 rows
#pragma unroll
      for (int j = 0; j < 4; ++j) {
        const f32x4 h4 = *(const f32x4*)&hlds[j * 256 + lane * 4];
#pragma unroll
        for (int gate = 0; gate < 3; ++gate)
#pragma unroll
          for (int q = 0; q < 4; ++q) {
            const f32x4 ww = w[gate][q][j];
            float s = a[gate][q];
            s = fmaf(h4.x, ww.x, s); s = fmaf(h4.y, ww.y, s);
            s = fmaf(h4.z, ww.z, s); s = fmaf(h4.w, ww.w, s);
            a[gate][q] = s;
          }
      }
#pragma unroll
      for (int m = 1; m < 64; m <<= 1)
#pragma unroll
        for (int gate = 0; gate < 3; ++gate)
#pragma unroll
          for (int q = 0; q < 4; ++q)
            a[gate][q] += __shfl_xor(a[gate][q], m, 64);
    }

    float h2s[4];
#pragma unroll
    for (int q = 0; q < 4; ++q) {
      const float r  = sigf(a[0][q] + gi_r[q]);     // b_ih+b_hh folded into gi_r/gi_z
      const float z  = sigf(a[1][q] + gi_z[q]);
      const float n  = tanh_fast(gi_n[q] + r * (a[2][q] + bn[q]));
      const float h2 = (1.0f - z) * n + z * hp[q];
      unsigned int bits = __float_as_uint(h2);
      if (bits == SENT) bits ^= 1u;                 // never store the sentinel
      hp[q]  = __uint_as_float(bits);
      h2s[q] = hp[q];
    }

    if (lane == 0) {
      // one vectorized fire-and-forget store of 4 contiguous h values
      f32x4 v4; v4.x = h2s[0]; v4.y = h2s[1]; v4.z = h2s[2]; v4.w = h2s[3];
      float* vp = (float*)hseq + (size_t)t * 1024 + hj0;
      asm volatile("global_store_dwordx4 %0, %1, off sc0 sc1"
                   :: "v"(vp), "v"(v4) : "memory");
#pragma unroll
      for (int q = 0; q < 4; ++q) wout_acc = fmaf(h2s[q], wo[q], wout_acc);
    }

    if (t > 0) __syncthreads();  // barrier2: hlds reads(t) done before fill(t+1)
  }

  if (lane == 0) atomicAdd(acc, wout_acc);
}

// ---------- K3: pure feat broadcast: feat[b][i] = hseq[i] for all 64 b ----------
__global__ __launch_bounds__(256) void k3_bcast(const float* __restrict__ hseq_f,
                                                float* __restrict__ outbuf)
{
  const int gtid = blockIdx.x * 256 + threadIdx.x;
  const float4* src = (const float4*)hseq_f;    // 65536 float4
  float4* dst = (float4*)outbuf;
  for (int q = gtid; q < 64 * 65536; q += 1024 * 256) {
    const int b = q >> 16, i4 = q & 65535;
    dst[(size_t)b * 65536 + i4] = src[i4];
  }
}

// ---------- K4: out[b] = sigmoid(acc + b_out) for all 64 b ----------
__global__ void k4_fin(const float* __restrict__ acc, const float* __restrict__ b_out,
                       float* __restrict__ outbuf)
{
  const float s = sigf(acc[0] + b_out[0]);
  outbuf[(size_t)16777216 + threadIdx.x] = s;
}

// ---------- launch ----------
extern "C" void kernel_launch(void* const* d_in, const int* in_sizes, int n_in,
                              void* d_out, int out_size, void* d_ws, size_t ws_size,
                              hipStream_t stream) {
  const int*   x     = (const int*)d_in[0];
  const float* emb   = (const float*)d_in[1];
  const float* w_ih  = (const float*)d_in[2];
  const float* w_hh  = (const float*)d_in[3];
  const float* b_ih  = (const float*)d_in[4];
  const float* b_hh  = (const float*)d_in[5];
  const float* w_out = (const float*)d_in[6];
  const float* b_out = (const float*)d_in[7];
  float* out = (float*)d_out;

  char* ws = (char*)d_ws;
  float*        gi   = (float*)ws;                       // 3,145,728 B
  unsigned int* hseq = (unsigned int*)(ws + 3145728);    // 1,048,576 B
  float*        acc  = (float*)(ws + 4194304);           // 4 B

  hipMemsetAsync(hseq, 0xAA, (size_t)256 * 1024 * 4, stream);  // sentinel init
  hipMemsetAsync(acc, 0, 4, stream);

  hipLaunchKernelGGL(k1_gi,    dim3(768),  dim3(256), 0, stream, x, emb, w_ih, b_ih, b_hh, gi);
  hipLaunchKernelGGL(k2_rec,   dim3(32),   dim3(512), 0, stream, w_hh, b_hh, gi, w_out, hseq, acc);
  hipLaunchKernelGGL(k3_bcast, dim3(1024), dim3(256), 0, stream, (const float*)hseq, out);
  hipLaunchKernelGGL(k4_fin,   dim3(1),    dim3(64),  0, stream, acc, b_out, out);
}